// Round 1
// baseline (1040.458 us; speedup 1.0000x reference)
//
#include <hip/hip_runtime.h>
#include <hip/hip_bf16.h>

// GARCH(1,1) path simulation.
// z: (N, T, D) fp32, params omega/alpha/beta/mu/sigma2_0: (D,) fp32.
// Recurrence per (n,d):
//   sig2_t = omega + alpha*eps2_{t-1} + beta*sig2_{t-1}; clamp; eps = sqrt(sig2)*z_t
//   x_t = mu + eps; eps2_t = eps*eps
// One thread per path n, both d=0,1 chains in registers.
// Layout [n][t][d] => one float4 = 2 timesteps x 2 dims, fully used per thread.

#define GARCH_N 32768
#define GARCH_T 2048
#define GARCH_D 2
#define F4_PER_CHAIN (GARCH_T * GARCH_D / 4)   // 1024
#define CHUNK 8                                 // float4 per inner iter = 16 steps

__global__ __launch_bounds__(128) void garch_kernel(
    const float4* __restrict__ z4,
    const float* __restrict__ omega,
    const float* __restrict__ alpha,
    const float* __restrict__ beta,
    const float* __restrict__ mu,
    const float* __restrict__ sigma2_0,
    float4* __restrict__ x4)
{
    const int n = blockIdx.x * blockDim.x + threadIdx.x;
    if (n >= GARCH_N) return;

    // per-dimension params (wave-uniform loads)
    const float o0 = omega[0], o1 = omega[1];
    const float a0 = alpha[0], a1 = alpha[1];
    const float b0 = beta[0],  b1 = beta[1];
    const float m0 = mu[0],    m1 = mu[1];

    // carry state
    float s2a = sigma2_0[0], s2b = sigma2_0[1];   // sigma^2 for d=0,1
    float e2a = 0.0f,        e2b = 0.0f;          // eps^2  for d=0,1

    const float4* __restrict__ zp = z4 + (size_t)n * F4_PER_CHAIN;
    float4* __restrict__ xp       = x4 + (size_t)n * F4_PER_CHAIN;

    for (int c = 0; c < F4_PER_CHAIN; c += CHUNK) {
        float4 in[CHUNK];
        #pragma unroll
        for (int j = 0; j < CHUNK; ++j) in[j] = zp[c + j];

        float4 out[CHUNK];
        #pragma unroll
        for (int j = 0; j < CHUNK; ++j) {
            const float4 v = in[j];
            // ---- step t (z = v.x for d0, v.y for d1) ----
            s2a = fmaf(b0, s2a, fmaf(a0, e2a, o0));
            s2a = fmaxf(s2a, 1e-12f);
            float ea = sqrtf(s2a) * v.x;
            float xa = m0 + ea;
            e2a = ea * ea;

            s2b = fmaf(b1, s2b, fmaf(a1, e2b, o1));
            s2b = fmaxf(s2b, 1e-12f);
            float eb = sqrtf(s2b) * v.y;
            float xb = m1 + eb;
            e2b = eb * eb;

            // ---- step t+1 (z = v.z for d0, v.w for d1) ----
            s2a = fmaf(b0, s2a, fmaf(a0, e2a, o0));
            s2a = fmaxf(s2a, 1e-12f);
            float ec = sqrtf(s2a) * v.z;
            float xc = m0 + ec;
            e2a = ec * ec;

            s2b = fmaf(b1, s2b, fmaf(a1, e2b, o1));
            s2b = fmaxf(s2b, 1e-12f);
            float ed = sqrtf(s2b) * v.w;
            float xd = m1 + ed;
            e2b = ed * ed;

            out[j] = make_float4(xa, xb, xc, xd);
        }

        #pragma unroll
        for (int j = 0; j < CHUNK; ++j) xp[c + j] = out[j];
    }
}

extern "C" void kernel_launch(void* const* d_in, const int* in_sizes, int n_in,
                              void* d_out, int out_size, void* d_ws, size_t ws_size,
                              hipStream_t stream)
{
    const float4* z4      = (const float4*)d_in[0];
    const float* omega    = (const float*)d_in[1];
    const float* alpha    = (const float*)d_in[2];
    const float* beta     = (const float*)d_in[3];
    const float* mu       = (const float*)d_in[4];
    const float* sigma2_0 = (const float*)d_in[5];
    float4* x4            = (float4*)d_out;

    const int block = 128;
    const int grid  = (GARCH_N + block - 1) / block;   // 256 blocks = 1/CU
    garch_kernel<<<grid, block, 0, stream>>>(z4, omega, alpha, beta, mu, sigma2_0, x4);
}

// Round 3
// 992.662 us; speedup vs baseline: 1.0481x; 1.0481x over previous
//
#include <hip/hip_runtime.h>
#include <hip/hip_bf16.h>

// GARCH(1,1) path simulation — round 2 (resubmitted unchanged after infra
// timeout; never measured).
// One thread per path n, both d=0,1 chains in registers (arithmetic identical
// to round-1 kernel, which matched the JAX reference bitwise: absmax=0.0).
//
// Round-1 diagnosis: ~2.6 TB/s effective (41% of achievable). Theory: DRAM
// locality — each stream advanced in 64B quanta, 32768 interleaved streams.
// Fix: 256B bursts per stream (CHUNK=16 float4) + explicit double-buffered
// register prefetch so the next chunk's 16 loads are in flight during the
// current chunk's dependent compute chain. Buffers use only compile-time
// indices (runtime-indexed arrays would spill to scratch).

#define GARCH_N 32768
#define GARCH_T 2048
#define F4_PER_CHAIN (GARCH_T * 2 / 4)   // 1024 float4 per path
#define CHUNK 16                          // float4 per chunk = 256B = 32 steps
#define NCHUNK (F4_PER_CHAIN / CHUNK)     // 64 (even)

struct GarchState {
    float s2a, s2b, e2a, e2b;
    float o0, o1, a0, a1, b0, b1, m0, m1;
};

// Compute 32 steps (16 float4) and store results. Same op order as round 1
// (bitwise-exact vs reference): fmaf(b, s2, fmaf(a, e2, o)), fmaxf clamp,
// sqrtf * z, mu + eps.
__device__ __forceinline__ void garch_chunk(const float4 (&in)[CHUNK],
                                            float4* __restrict__ xp, int c,
                                            GarchState& st)
{
    #pragma unroll
    for (int j = 0; j < CHUNK; ++j) {
        const float4 v = in[j];

        st.s2a = fmaf(st.b0, st.s2a, fmaf(st.a0, st.e2a, st.o0));
        st.s2a = fmaxf(st.s2a, 1e-12f);
        float ea = sqrtf(st.s2a) * v.x;
        float xa = st.m0 + ea;
        st.e2a = ea * ea;

        st.s2b = fmaf(st.b1, st.s2b, fmaf(st.a1, st.e2b, st.o1));
        st.s2b = fmaxf(st.s2b, 1e-12f);
        float eb = sqrtf(st.s2b) * v.y;
        float xb = st.m1 + eb;
        st.e2b = eb * eb;

        st.s2a = fmaf(st.b0, st.s2a, fmaf(st.a0, st.e2a, st.o0));
        st.s2a = fmaxf(st.s2a, 1e-12f);
        float ec = sqrtf(st.s2a) * v.z;
        float xc = st.m0 + ec;
        st.e2a = ec * ec;

        st.s2b = fmaf(st.b1, st.s2b, fmaf(st.a1, st.e2b, st.o1));
        st.s2b = fmaxf(st.s2b, 1e-12f);
        float ed = sqrtf(st.s2b) * v.w;
        float xd = st.m1 + ed;
        st.e2b = ed * ed;

        xp[c + j] = make_float4(xa, xb, xc, xd);
    }
}

__global__ __launch_bounds__(128) void garch_kernel(
    const float4* __restrict__ z4,
    const float* __restrict__ omega,
    const float* __restrict__ alpha,
    const float* __restrict__ beta,
    const float* __restrict__ mu,
    const float* __restrict__ sigma2_0,
    float4* __restrict__ x4)
{
    const int n = blockIdx.x * blockDim.x + threadIdx.x;
    if (n >= GARCH_N) return;

    GarchState st;
    st.o0 = omega[0]; st.o1 = omega[1];
    st.a0 = alpha[0]; st.a1 = alpha[1];
    st.b0 = beta[0];  st.b1 = beta[1];
    st.m0 = mu[0];    st.m1 = mu[1];
    st.s2a = sigma2_0[0]; st.s2b = sigma2_0[1];
    st.e2a = 0.0f;        st.e2b = 0.0f;

    const float4* __restrict__ zp = z4 + (size_t)n * F4_PER_CHAIN;
    float4* __restrict__ xp       = x4 + (size_t)n * F4_PER_CHAIN;

    float4 bufA[CHUNK], bufB[CHUNK];

    // prologue: load chunk 0 into A
    #pragma unroll
    for (int j = 0; j < CHUNK; ++j) bufA[j] = zp[j];

    // main loop unrolled by 2 so buffer selection is compile-time (no scratch)
    for (int c = 0; c < NCHUNK; c += 2) {
        // issue loads for chunk c+1 into B (always valid: c+1 <= NCHUNK-1)
        #pragma unroll
        for (int j = 0; j < CHUNK; ++j) bufB[j] = zp[(c + 1) * CHUNK + j];

        // compute + store chunk c from A (waits only on A's loads; B stays in flight)
        garch_chunk(bufA, xp, c * CHUNK, st);

        // issue loads for chunk c+2 into A (guard final iteration)
        if (c + 2 < NCHUNK) {
            #pragma unroll
            for (int j = 0; j < CHUNK; ++j) bufA[j] = zp[(c + 2) * CHUNK + j];
        }

        // compute + store chunk c+1 from B
        garch_chunk(bufB, xp, (c + 1) * CHUNK, st);
    }
}

extern "C" void kernel_launch(void* const* d_in, const int* in_sizes, int n_in,
                              void* d_out, int out_size, void* d_ws, size_t ws_size,
                              hipStream_t stream)
{
    const float4* z4      = (const float4*)d_in[0];
    const float* omega    = (const float*)d_in[1];
    const float* alpha    = (const float*)d_in[2];
    const float* beta     = (const float*)d_in[3];
    const float* mu       = (const float*)d_in[4];
    const float* sigma2_0 = (const float*)d_in[5];
    float4* x4            = (float4*)d_out;

    const int block = 128;
    const int grid  = (GARCH_N + block - 1) / block;   // 256 blocks = 1/CU
    garch_kernel<<<grid, block, 0, stream>>>(z4, omega, alpha, beta, mu, sigma2_0, x4);
}

// Round 6
// 971.691 us; speedup vs baseline: 1.0708x; 1.0216x over previous
//
#include <hip/hip_runtime.h>
#include <hip/hip_bf16.h>

// GARCH(1,1) path simulation — round 4 design: LDS-staged coalescing, both
// directions. (Third submission attempt; never measured due to GPU timeouts.)
//
// Round-3 diagnosis: ~405us, VALUBusy 18%, HBM ~29% peak, write amplification
// 1.22x. Limiter: address-processing — every wave mem instr touches 64 distinct
// cache lines (lanes 16KiB apart) = 64 L1 transactions/instr (~109us/CU floor).
// Fix: coalesce through LDS. 1-wave blocks (64 threads = 64 paths) need NO
// barriers: DS ops from one wave execute in order. Pipeline per 256B tile:
//   A: 16x global_load_lds(width16), linear LDS dest, PRE-SWIZZLED global src
//      (rule #21/m173: gload_lds dest is base+lane*16 only; swizzle the source)
//   B: own-row swizzled ds_read_b128 (XOR j^(row&15) kills the 256B-stride
//      16-way bank conflict -> ~2-way, free), compute 32 steps (arithmetic
//      bitwise-identical to rounds 1-3: absmax was 0.0), write results in-place
//   C: linear ds_read_b128 + coalesced stores (16 lanes = contiguous 256B)
// Double-buffered with counted s_waitcnt vmcnt(16): VMEM ops retire in order,
// so outstanding<=16 => everything older than the just-issued 16 loads landed.

#define NPATH      32768
#define PPB        64                    // paths per block = 1 wave
#define F4_PATH    1024                  // float4 per path (2048*2/4)
#define CF4        16                    // float4 per path per tile (256B)
#define NTILE      (F4_PATH / CF4)       // 64
#define LDSF4      (PPB * CF4)           // 1024 float4 = 16KB per buffer

struct GS { float s2a, s2b, e2a, e2b, o0, o1, a0, a1, b0, b1, m0, m1; };

// A-phase: issue 16 async global->LDS loads for tile c into Lb (linear dest).
// LDS slot (r = flat/16, col s = flat%16) receives global col (s ^ (r&15)).
__device__ __forceinline__ void issueA(const float4* __restrict__ zb, float4* Lb,
                                       int c, int w4, int s)
{
    #pragma unroll
    for (int i = 0; i < 16; ++i) {
        const int r   = i * 4 + w4;          // row this lane covers
        const int col = s ^ (r & 15);        // inverse swizzle on the SOURCE
        const float4* src = zb + (size_t)r * F4_PATH + (size_t)c * CF4 + col;
        __builtin_amdgcn_global_load_lds(
            (const __attribute__((address_space(1))) void*)src,
            (__attribute__((address_space(3))) void*)(Lb + i * 64),
            16, 0, 0);
    }
}

// C-phase: linear LDS reads (contiguous 1KB per instr, ~2-way = free) +
// coalesced stores to the matching swizzled global position.
__device__ __forceinline__ void doC(float4* __restrict__ xb, const float4* Lb,
                                    int c, int w, int w4, int s)
{
    float4 v[16];
    #pragma unroll
    for (int i = 0; i < 16; ++i) v[i] = Lb[i * 64 + w];
    #pragma unroll
    for (int i = 0; i < 16; ++i) {
        const int r   = i * 4 + w4;
        const int col = s ^ (r & 15);
        xb[(size_t)r * F4_PATH + (size_t)c * CF4 + col] = v[i];
    }
}

// B-phase: own-row swizzled reads, 32 GARCH steps (bitwise-exact op order),
// in-place swizzled writes. Same-wave DS ordering makes this barrier-free.
__device__ __forceinline__ void doB(float4* Lb, int w, GS& st)
{
    const int m = w & 15;
    float4 in[16];
    #pragma unroll
    for (int j = 0; j < 16; ++j) in[j] = Lb[w * CF4 + (j ^ m)];

    #pragma unroll
    for (int j = 0; j < 16; ++j) {
        const float4 v = in[j];

        st.s2a = fmaf(st.b0, st.s2a, fmaf(st.a0, st.e2a, st.o0));
        st.s2a = fmaxf(st.s2a, 1e-12f);
        float ea = sqrtf(st.s2a) * v.x;
        float xa = st.m0 + ea;
        st.e2a = ea * ea;

        st.s2b = fmaf(st.b1, st.s2b, fmaf(st.a1, st.e2b, st.o1));
        st.s2b = fmaxf(st.s2b, 1e-12f);
        float eb = sqrtf(st.s2b) * v.y;
        float xb = st.m1 + eb;
        st.e2b = eb * eb;

        st.s2a = fmaf(st.b0, st.s2a, fmaf(st.a0, st.e2a, st.o0));
        st.s2a = fmaxf(st.s2a, 1e-12f);
        float ec = sqrtf(st.s2a) * v.z;
        float xc = st.m0 + ec;
        st.e2a = ec * ec;

        st.s2b = fmaf(st.b1, st.s2b, fmaf(st.a1, st.e2b, st.o1));
        st.s2b = fmaxf(st.s2b, 1e-12f);
        float ed = sqrtf(st.s2b) * v.w;
        float xd = st.m1 + ed;
        st.e2b = ed * ed;

        in[j] = make_float4(xa, xb, xc, xd);
    }

    #pragma unroll
    for (int j = 0; j < 16; ++j) Lb[w * CF4 + (j ^ m)] = in[j];
}

#define VMWAIT16() do {                                   \
    __builtin_amdgcn_sched_barrier(0);                    \
    asm volatile("s_waitcnt vmcnt(16)" ::: "memory");     \
    __builtin_amdgcn_sched_barrier(0);                    \
} while (0)

__global__ __launch_bounds__(PPB) void garch_kernel(
    const float4* __restrict__ z4,
    const float* __restrict__ omega,
    const float* __restrict__ alpha,
    const float* __restrict__ beta,
    const float* __restrict__ mu,
    const float* __restrict__ sigma2_0,
    float4* __restrict__ x4)
{
    __shared__ float4 lds[2][LDSF4];

    const int w  = threadIdx.x;
    const int w4 = w >> 4;
    const int s  = w & 15;

    const size_t pbase = (size_t)blockIdx.x * PPB;
    const float4* __restrict__ zb = z4 + pbase * F4_PATH;
    float4* __restrict__ xb       = x4 + pbase * F4_PATH;

    GS st;
    st.o0 = omega[0]; st.o1 = omega[1];
    st.a0 = alpha[0]; st.a1 = alpha[1];
    st.b0 = beta[0];  st.b1 = beta[1];
    st.m0 = mu[0];    st.m1 = mu[1];
    st.s2a = sigma2_0[0]; st.s2b = sigma2_0[1];
    st.e2a = 0.0f;        st.e2b = 0.0f;

    // prologue: prefetch tiles 0 and 1; wait for tile 0 (32 issued, <=16 left
    // implies the older 16 — tile 0 — all landed: VMEM ops retire in order).
    issueA(zb, &lds[0][0], 0, w4, s);
    issueA(zb, &lds[1][0], 1, w4, s);
    VMWAIT16();
    doB(&lds[0][0], w, st);

    for (int k = 1; k < NTILE; ++k) {
        // C(k-1): drain previous tile's results (frees buf[(k-1)&1] logically
        // after its ds_reads; store data deps force lgkm completion first)
        doC(xb, &lds[(k - 1) & 1][0], k - 1, w, w4, s);
        __builtin_amdgcn_sched_barrier(0);
        // A(k+1): refill the buffer C just vacated ((k+1)&1 == (k-1)&1).
        // k=63 wraps to tile 0 into buf[0] — harmless dead loads, keeps the
        // vmcnt FIFO depth uniform so vmcnt(16) is always the right count.
        issueA(zb, &lds[(k + 1) & 1][0], (k + 1) & (NTILE - 1), w4, s);
        VMWAIT16();                       // guarantees A(k) landed
        doB(&lds[k & 1][0], w, st);       // compute tile k
    }
    doC(xb, &lds[(NTILE - 1) & 1][0], NTILE - 1, w, w4, s);
}

extern "C" void kernel_launch(void* const* d_in, const int* in_sizes, int n_in,
                              void* d_out, int out_size, void* d_ws, size_t ws_size,
                              hipStream_t stream)
{
    const float4* z4      = (const float4*)d_in[0];
    const float* omega    = (const float*)d_in[1];
    const float* alpha    = (const float*)d_in[2];
    const float* beta     = (const float*)d_in[3];
    const float* mu       = (const float*)d_in[4];
    const float* sigma2_0 = (const float*)d_in[5];
    float4* x4            = (float4*)d_out;

    const int block = PPB;                 // 64 = 1 wave
    const int grid  = NPATH / PPB;         // 512 blocks = 2 per CU
    garch_kernel<<<grid, block, 0, stream>>>(z4, omega, alpha, beta, mu, sigma2_0, x4);
}